// Round 8
// baseline (213.024 us; speedup 1.0000x reference)
//
#include <hip/hip_runtime.h>
#include <hip/hip_bf16.h>
#include <math.h>

#define NBATCH 16
#define NA     128
#define CH     512
#define EFEAT  30

typedef __attribute__((ext_vector_type(8))) short          bf16x8;
typedef __attribute__((ext_vector_type(4))) float          f32x4;
typedef __attribute__((ext_vector_type(2))) float          f32x2;
typedef __attribute__((ext_vector_type(8))) unsigned short ushort8;
typedef __attribute__((ext_vector_type(4))) unsigned short ushort4_t;

__device__ __forceinline__ float selu_f(float x) {
    const float SA = 1.7580993408473766f;     // scale*alpha
    float e = __expf(x);
    return x > 0.0f ? 1.0507009873554805f * x : fmaf(SA, e, -SA);
}

__device__ __forceinline__ unsigned short f2bf(float f) {
    __hip_bfloat16 h = __float2bfloat16(f);   // RNE
    return *reinterpret_cast<unsigned short*>(&h);
}

// Load the k = g*8 .. g*8+7 slice of a 30-float row as a bf16x8 fragment.
// k=30 pad slot <- slot30, k=31 <- 0 (only the g==3 slice has those).
// All float2 offsets (row30*4B bases are multiples of 8B; +2m*4B keeps 8B
// alignment) are provably aligned; last real pair k=28,29 stays in bounds.
__device__ __forceinline__ bf16x8 load_row30(const float* __restrict__ base,
                                             int g, float slot30) {
    ushort8 t;
    const f32x2 p0 = *(const f32x2*)(base + g * 8 + 0);
    const f32x2 p1 = *(const f32x2*)(base + g * 8 + 2);
    const f32x2 p2 = *(const f32x2*)(base + g * 8 + 4);
    t[0] = f2bf(p0.x); t[1] = f2bf(p0.y);
    t[2] = f2bf(p1.x); t[3] = f2bf(p1.y);
    t[4] = f2bf(p2.x); t[5] = f2bf(p2.y);
    if (g < 3) {
        const f32x2 p3 = *(const f32x2*)(base + g * 8 + 6);
        t[6] = f2bf(p3.x); t[7] = f2bf(p3.y);
    } else {
        t[6] = f2bf(slot30); t[7] = 0;
    }
    return *(bf16x8*)&t;
}

// -------------------------------------------------------------------------
// Kernel 1 (v3): edge filter + SELU + mask + aggregation.
// BARRIER-FREE, LDS-FREE, COMPACTION-FREE. One block per (b,i) row.
//   S[c,j] = fW[c,:30]·e[row,j,:30] + fb[c]   (bias via k=30 pad: e slot=1.0,
//                                              fW slot=fb[c])
//   h1[c] = sum_j em[row,j] * selu(S[c,j]) * h[b,j,c]
// All operands load inline global->VGPR (L2-hot panels; XCD swizzle keeps a
// 512 KB h/e working set per XCD L2). Masked j's are computed then zeroed by
// emj — dead-edge compute is cheap, serialization was not. 8 j-tiles of 16.
// D layout: col=lane&15=j, row=(lane>>4)*4+q=c -> h is one float4/lane;
// j-reduce = shfl_xor{1,2,4,8}. Zero __syncthreads, zero LDS.
// -------------------------------------------------------------------------
__global__ __launch_bounds__(256, 4)
void k_edge_mfma(const float* __restrict__ h, const float* __restrict__ e,
                 const float* __restrict__ node_mask, const float* __restrict__ edge_mask,
                 const float* __restrict__ fW, const float* __restrict__ fb,
                 unsigned short* __restrict__ z)
{
    const int row = (blockIdx.x & 7) * 256 + (blockIdx.x >> 3);  // XCD swizzle
    if (node_mask[row] == 0.0f) return;          // block-uniform early exit
    const int b = row >> 7;

    const int tid  = threadIdx.x;
    const int lane = tid & 63;
    const int wv   = tid >> 6;
    const int s    = lane & 15;                  // fragment col (j within tile)
    const int g    = lane >> 4;                  // k-group / c-row-group
    const int cbase = wv * 128;                  // wave owns 128 channels

    // A-fragments: fW row c, k-slice g*8..+7, fb folded into k=30 slot.
    bf16x8 afrag[8];
    #pragma unroll
    for (int cf = 0; cf < 8; ++cf) {
        const int c = cbase + cf * 16 + s;
        afrag[cf] = load_row30(fW + (size_t)c * EFEAT, g, fb[c]);
    }

    // z-row echo of h (independent; issue early)
    unsigned short* zrow = z + (size_t)row * (2 * CH);
    const float* hrow = h + (size_t)row * CH;
    zrow[tid]       = f2bf(hrow[tid]);
    zrow[tid + 256] = f2bf(hrow[tid + 256]);

    const float* erow = e + (size_t)row * (NA * EFEAT);
    const float* emrow = edge_mask + (size_t)row * NA;

    f32x4 acc[8];
    #pragma unroll
    for (int cf = 0; cf < 8; ++cf) acc[cf] = (f32x4){0.f, 0.f, 0.f, 0.f};

    #pragma unroll 2
    for (int jt = 0; jt < 8; ++jt) {
        const int j = jt * 16 + s;               // this lane's j (no compaction)
        const float emj = emrow[j];              // 0 or 1
        const bf16x8 bfrag = load_row30(erow + (size_t)j * EFEAT, g, 1.0f);
        const float* hbase = h + ((size_t)(b * NA) + j) * CH + cbase;
        f32x4 hv[8];
        #pragma unroll
        for (int cf = 0; cf < 8; ++cf)           // 8 independent loads in flight
            hv[cf] = *(const f32x4*)&hbase[cf * 16 + g * 4];
        #pragma unroll
        for (int cf = 0; cf < 8; ++cf) {
            f32x4 S = __builtin_amdgcn_mfma_f32_16x16x32_bf16(
                          afrag[cf], bfrag, (f32x4){0.f, 0.f, 0.f, 0.f}, 0, 0, 0);
            #pragma unroll
            for (int q = 0; q < 4; ++q) {
                const float sv = selu_f(S[q]);           // bias already in S
                acc[cf][q] = fmaf(emj, sv * hv[cf][q], acc[cf][q]);
            }
        }
    }

    // reduce over j across the 16 s-lanes of each g-group
    #pragma unroll
    for (int m = 1; m <= 8; m <<= 1)
        #pragma unroll
        for (int cf = 0; cf < 8; ++cf)
            #pragma unroll
            for (int q = 0; q < 4; ++q)
                acc[cf][q] += __shfl_xor(acc[cf][q], m, 64);

    if (s == 0) {                                // lanes 0,16,32,48 hold sums
        #pragma unroll
        for (int cf = 0; cf < 8; ++cf) {
            const int c0 = cbase + cf * 16 + g * 4;
            ushort4_t o;
            #pragma unroll
            for (int q = 0; q < 4; ++q) o[q] = f2bf(acc[cf][q]);
            *(ushort4_t*)&zrow[CH + c0] = o;
        }
    }
}

// -------------------------------------------------------------------------
// Kernel 2: node MLP bf16 MFMA GEMM (R6 version — measured ~19 µs implied).
// C = z(2048x1024 bf16) @ wW^T; out = selu(C+wb)*nm + h.
// 32x32 tiles, BK=128 -> grid 1024 (4 blocks/CU, 16 waves/CU). Both operands
// LDS-staged (rows padded to 136 shorts); wW f32->bf16 during reg-staging.
// 4 waves = 2x2 16x16 quadrants, 8 K-steps x 4 MFMA. XCD swizzle shares the
// 2MB wW panel. Dead z rows are 0xAA poison (finite bf16); nm=0 masks them.
// -------------------------------------------------------------------------
__global__ __launch_bounds__(256, 4)
void k_node_mlp(const float* __restrict__ h, const unsigned short* __restrict__ z,
                const float* __restrict__ node_mask,
                const float* __restrict__ wW, const float* __restrict__ wb,
                float* __restrict__ out)
{
    __shared__ short As[32][136];
    __shared__ short Bs[32][136];
    const int tid = threadIdx.x;
    const int bid = (blockIdx.x & 7) * 128 + (blockIdx.x >> 3);  // 1024 = 8*128
    const int m0  = (bid >> 4) * 32;
    const int n0  = (bid & 15) * 32;
    const int lane = tid & 63, wv = tid >> 6;
    const int wr = wv >> 1, wc = wv & 1;
    const int s  = lane & 15, g = lane >> 4;

    const int arow = tid >> 3;                   // staging: 8 threads/row
    const int akb  = (tid & 7) * 16;             // 16 elems each

    f32x4 acc = {0.f, 0.f, 0.f, 0.f};

    for (int ks = 0; ks < 2 * CH; ks += 128) {
        // A: z tile (bf16 passthrough)
        const ushort8 a0 = *(const ushort8*)&z[(size_t)(m0 + arow) * (2 * CH) + ks + akb];
        const ushort8 a1 = *(const ushort8*)&z[(size_t)(m0 + arow) * (2 * CH) + ks + akb + 8];
        // B: wW tile f32 -> bf16
        const float* wsrc = wW + (size_t)(n0 + arow) * (2 * CH) + ks + akb;
        const f32x4 u0 = *(const f32x4*)&wsrc[0];
        const f32x4 u1 = *(const f32x4*)&wsrc[4];
        const f32x4 u2 = *(const f32x4*)&wsrc[8];
        const f32x4 u3 = *(const f32x4*)&wsrc[12];
        ushort8 t0, t1;
        #pragma unroll
        for (int q = 0; q < 4; ++q) {
            t0[q] = f2bf(u0[q]); t0[q + 4] = f2bf(u1[q]);
            t1[q] = f2bf(u2[q]); t1[q + 4] = f2bf(u3[q]);
        }
        *(ushort8*)&As[arow][akb]     = a0;
        *(ushort8*)&As[arow][akb + 8] = a1;
        *(ushort8*)&Bs[arow][akb]     = t0;
        *(ushort8*)&Bs[arow][akb + 8] = t1;
        __syncthreads();
        #pragma unroll
        for (int kk = 0; kk < 128; kk += 32) {
            const bf16x8 af = *(const bf16x8*)&As[wr * 16 + s][kk + g * 8];
            const bf16x8 bf = *(const bf16x8*)&Bs[wc * 16 + s][kk + g * 8];
            acc = __builtin_amdgcn_mfma_f32_16x16x32_bf16(af, bf, acc, 0, 0, 0);
        }
        __syncthreads();
    }

    // epilogue: D col=s (n), row=g*4+q (m)
    const int r0 = m0 + wr * 16 + g * 4;
    const int c  = n0 + wc * 16 + s;
    const float wbv = wb[c];
    const f32x4 nmv = *(const f32x4*)&node_mask[r0];
    #pragma unroll
    for (int q = 0; q < 4; ++q) {
        const size_t gi = (size_t)(r0 + q) * CH + c;
        out[gi] = selu_f(acc[q] + wbv) * nmv[q] + h[gi];
    }
}

extern "C" void kernel_launch(void* const* d_in, const int* in_sizes, int n_in,
                              void* d_out, int out_size, void* d_ws, size_t ws_size,
                              hipStream_t stream)
{
    (void)in_sizes; (void)n_in; (void)out_size; (void)ws_size;
    const float* h  = (const float*)d_in[0];
    const float* e  = (const float*)d_in[1];
    const float* nm = (const float*)d_in[2];
    const float* em = (const float*)d_in[3];
    const float* fW = (const float*)d_in[4];
    const float* fb = (const float*)d_in[5];
    const float* wW = (const float*)d_in[6];
    const float* wb = (const float*)d_in[7];
    float* out = (float*)d_out;
    unsigned short* z = (unsigned short*)d_ws;   // 2048 x 1024 bf16 = 4 MB

    k_edge_mfma<<<NBATCH * NA, 256, 0, stream>>>(h, e, nm, em, fW, fb, z);
    k_node_mlp<<<(NBATCH * NA / 32) * (CH / 32), 256, 0, stream>>>(h, z, nm, wW, wb, out);
}